// Round 6
// baseline (290.857 us; speedup 1.0000x reference)
//
#include <hip/hip_runtime.h>
#include <hip/hip_bf16.h>
#include <cstdint>
#include <cstddef>

typedef __hip_bfloat16 bf16;
typedef __attribute__((ext_vector_type(8))) short short8;   // 8 bf16 = 4 VGPRs
typedef __attribute__((ext_vector_type(4))) short s4v;      // 4 bf16 = 2 VGPRs
typedef __attribute__((ext_vector_type(4))) float floatx4;

#define B_ 2
#define S_ 2048
#define D_ 1024
#define H_ 16
#define DK_ 64
#define M_ 4096
#define HEADELEMS 131072   // S_*DK_ per (b,h)
#define TILEELEMS 4096     // 64*64 per 64-token tile
#define QSCALE 0.1803368801111204f   // 0.125 * log2(e), folded into Q projection

struct __align__(8) bf16x4 { bf16 x, y, z, w; };
struct __align__(4) bf16x2 { bf16 x, y; };

__device__ __forceinline__ floatx4 mfma16(short8 a, short8 b, floatx4 c) {
  return __builtin_amdgcn_mfma_f32_16x16x32_bf16(a, b, c, 0, 0, 0);
}
__device__ __forceinline__ void gl_lds16(const bf16* g, bf16* l) {
  __builtin_amdgcn_global_load_lds((const __attribute__((address_space(1))) void*)g,
                                   (__attribute__((address_space(3))) void*)l, 16, 0, 0);
}
__device__ __forceinline__ float bs2f(short s) {
  bf16 b = *reinterpret_cast<bf16*>(&s);
  return __bfloat162float(b);
}
__device__ __forceinline__ s4v pack4(float p0, float p1, float p2, float p3) {
  union { __hip_bfloat162 h; short2 s; } ua, ub;
  ua.h = __float22bfloat162_rn(make_float2(p0, p1));
  ub.h = __float22bfloat162_rn(make_float2(p2, p3));
  s4v r = {ua.s.x, ua.s.y, ub.s.x, ub.s.y};
  return r;
}
__device__ __forceinline__ float fast_exp2(float x) {
#if __has_builtin(__builtin_amdgcn_exp2f)
  return __builtin_amdgcn_exp2f(x);    // raw v_exp_f32 (no OCML range fixup)
#else
  float r; asm("v_exp_f32 %0, %1" : "=v"(r) : "v"(x)); return r;
#endif
}

// ---------------- fused prep: fp32->bf16 converts + weight transposes + mask detect ----------------
__global__ void prep_kernel(const float* __restrict__ q_in, const float* __restrict__ k_in,
                            const float* __restrict__ v_in,
                            const float* __restrict__ Wq, const float* __restrict__ Wk,
                            const float* __restrict__ Wv, const float* __restrict__ Wo,
                            bf16* __restrict__ xq, bf16* __restrict__ xk, bf16* __restrict__ xv,
                            bf16* __restrict__ wqt, bf16* __restrict__ wkt,
                            bf16* __restrict__ wvt, bf16* __restrict__ wot,
                            const unsigned int* __restrict__ pmask, int* __restrict__ flag) {
  __shared__ bf16 tile[64][66];
  __shared__ int sbyte;
  const int blk = blockIdx.x;
  const int tid = threadIdx.x;
  if (blk < 12288) {
    const int z = blk >> 12;
    const int i = ((blk & 4095) << 8) | tid;
    const float* src = (z == 0) ? q_in : (z == 1) ? k_in : v_in;
    bf16* dst = (z == 0) ? xq : (z == 1) ? xk : xv;
    float4 v = ((const float4*)src)[i];
    bf16x4 o = { __float2bfloat16(v.x), __float2bfloat16(v.y),
                 __float2bfloat16(v.z), __float2bfloat16(v.w) };
    ((bf16x4*)dst)[i] = o;
  } else if (blk < 13312) {
    const int t = blk - 12288;
    const int z = t >> 8;
    const int rc = t & 255;
    const int r0 = (rc >> 4) * 64, c0 = (rc & 15) * 64;
    const float* src = (z == 0) ? Wq : (z == 1) ? Wk : (z == 2) ? Wv : Wo;
    bf16* dst = (z == 0) ? wqt : (z == 1) ? wkt : (z == 2) ? wvt : wot;
    const int lr = tid >> 4;
    const int lc4 = (tid & 15) * 4;
#pragma unroll
    for (int i = 0; i < 4; ++i) {
      const int r = lr + i * 16;
      float4 v = *(const float4*)(src + (size_t)(r0 + r) * D_ + c0 + lc4);
      tile[r][lc4 + 0] = __float2bfloat16(v.x);
      tile[r][lc4 + 1] = __float2bfloat16(v.y);
      tile[r][lc4 + 2] = __float2bfloat16(v.z);
      tile[r][lc4 + 3] = __float2bfloat16(v.w);
    }
    __syncthreads();
    const int orr = tid & 63;
    const int oc0 = tid >> 6;
#pragma unroll
    for (int j = 0; j < 16; ++j) {
      const int oc = oc0 + j * 4;
      dst[(size_t)(c0 + oc) * D_ + r0 + orr] = tile[orr][oc];
    }
  } else {
    if (tid == 0) sbyte = 0;
    __syncthreads();
    for (int i = tid; i < (B_ * S_) / 4; i += 256) {
      const unsigned int v = pmask[i];
      if (((v & 0xFEFEFEFEu) == 0u) && ((v & 0xFFFFFF00u) != 0u)) sbyte = 1;
    }
    __syncthreads();
    if (tid == 0) *flag = sbyte;
  }
}

// ---------------- bf16 GEMM, C = A[M,K] * W[N,K]^T + bias ----------------
// BK=64 (128B LDS rows = bank cycle), XOR-swizzled staging (chunk ^= row&7) via
// pre-swizzled global_load_lds SOURCE addresses -> 2-way (free) ds_read_b128.
// Double-buffered 2-phase loop: stage(k+1) || ds_read+MFMA(k), one barrier/step.
// Grid (Mtiles, Ntiles, z): blockIdx.x = m-tile so the 8 blocks sharing an
// A-panel land on ONE XCD -> A-panel L2-local.
template<int MT>
__global__ __launch_bounds__(256, 2) void gemm_k(
    const bf16* __restrict__ A0, const bf16* __restrict__ A1, const bf16* __restrict__ A2,
    const bf16* __restrict__ W0, const bf16* __restrict__ W1, const bf16* __restrict__ W2,
    const float* __restrict__ b0, const float* __restrict__ b1, const float* __restrict__ b2,
    void* __restrict__ O0, void* __restrict__ O1, void* __restrict__ O2,
    const int mode01, const int Kd, const float sc)
{
  constexpr int ROWS = MT + 128;                    // A rows + B rows
  __shared__ __align__(16) bf16 sh[2 * ROWS * 64];  // two BK=64 buffers (64KB at MT=128)
  const int z = blockIdx.z;
  const bf16* A = (z == 0) ? A0 : (z == 1) ? A1 : A2;
  const bf16* W = (z == 0) ? W0 : (z == 1) ? W1 : W2;
  const float* bias = (z == 0) ? b0 : (z == 1) ? b1 : b2;
  void* Cout = (z == 0) ? O0 : (z == 1) ? O1 : O2;
  const int mode = (z == 2) ? 1 : mode01;
  const float scz = (z == 0) ? sc : 1.f;

  constexpr int MI = MT / 32;
  const int tid = threadIdx.x;
  const int wave = tid >> 6, lane = tid & 63;
  const int quad = lane >> 4, lc = lane & 15;
  const int wm = (wave >> 1) * (MT / 2), wn = (wave & 1) * 64;
  const int m0 = blockIdx.x * MT, n0 = blockIdx.y * 128;

  const floatx4 zero4 = {0.f, 0.f, 0.f, 0.f};
  floatx4 acc[MI][4];
#pragma unroll
  for (int mi = 0; mi < MI; ++mi)
#pragma unroll
    for (int ni = 0; ni < 4; ++ni) acc[mi][ni] = zero4;

  const int srow = lane >> 3;
  const int schunk = ((lane & 7) ^ srow) * 8;       // elems
  const bf16* Ag = A + (size_t)(m0 + wave * (MT / 4) + srow) * Kd + schunk;
  const bf16* Bg = W + (size_t)(n0 + wave * 32 + srow) * Kd + schunk;

  auto stage = [&](bf16* buf, int k0) {
    bf16* As0 = buf + wave * (MT / 4) * 64;
    bf16* Bs0 = buf + MT * 64 + wave * 32 * 64;
#pragma unroll
    for (int j = 0; j < MT / 32; ++j)
      gl_lds16(Ag + k0 + (size_t)(j * 8) * Kd, As0 + j * 512);
#pragma unroll
    for (int j = 0; j < 4; ++j)
      gl_lds16(Bg + k0 + (size_t)(j * 8) * Kd, Bs0 + j * 512);
  };

  stage(sh, 0);
  asm volatile("s_waitcnt vmcnt(0)" ::: "memory");
  __syncthreads();

  int cur = 0;
  for (int k0 = 0; k0 < Kd; k0 += 64) {
    bf16* cbuf = cur ? sh + ROWS * 64 : sh;
    bf16* nbuf = cur ? sh : sh + ROWS * 64;
    const bool more = (k0 + 64 < Kd);
    if (more) stage(nbuf, k0 + 64);                 // prefetch: hidden under reads+MFMA

    const bf16* Ar = cbuf;
    const bf16* Br = cbuf + MT * 64;
    short8 af[2][MI], bfr[2][4];
#pragma unroll
    for (int kk = 0; kk < 2; ++kk) {
#pragma unroll
      for (int i = 0; i < MI; ++i)
        af[kk][i] = *(const short8*)(Ar + (wm + i * 16 + lc) * 64
                                     + (((kk * 4 + quad) ^ (lc & 7)) * 8));
#pragma unroll
      for (int i = 0; i < 4; ++i)
        bfr[kk][i] = *(const short8*)(Br + (wn + i * 16 + lc) * 64
                                      + (((kk * 4 + quad) ^ (lc & 7)) * 8));
    }
#pragma unroll
    for (int kk = 0; kk < 2; ++kk)
#pragma unroll
      for (int mi = 0; mi < MI; ++mi)
#pragma unroll
        for (int ni = 0; ni < 4; ++ni)
          acc[mi][ni] = mfma16(af[kk][mi], bfr[kk][ni], acc[mi][ni]);

    __syncthreads();   // drains vmcnt(0): next buffer staged, this buffer free
    cur ^= 1;
  }

  if (mode == 2) {
    float* out = (float*)Cout;
#pragma unroll
    for (int mi = 0; mi < MI; ++mi)
#pragma unroll
      for (int ni = 0; ni < 4; ++ni) {
        const int col = n0 + wn + ni * 16 + lc;
        const float bv = bias[col];
        const int rbase = m0 + wm + mi * 16 + quad * 4;
#pragma unroll
        for (int r = 0; r < 4; ++r)
          out[(size_t)(rbase + r) * D_ + col] = acc[mi][ni][r] + bv;
      }
  } else {
    bf16* pool = sh + wave * 2048;
    float bvs[4];
#pragma unroll
    for (int ni = 0; ni < 4; ++ni) bvs[ni] = bias[n0 + wn + ni * 16 + lc];
    const int hcol = (n0 + wn) >> 6;
    const int mglob = m0 + wm;
    bf16* outb = (bf16*)Cout + (size_t)((mglob >> 11) * H_ + hcol) * HEADELEMS
               + (size_t)((mglob & (S_ - 1)) >> 6) * TILEELEMS;
#pragma unroll
    for (int half2 = 0; half2 < MI / 2; ++half2) {
#pragma unroll
      for (int mi2 = 0; mi2 < 2; ++mi2) {
        const int mi = half2 * 2 + mi2;
#pragma unroll
        for (int ni = 0; ni < 4; ++ni) {
          const int dkl = ni * 16 + lc;
#pragma unroll
          for (int r = 0; r < 4; ++r) {
            const float v = (acc[mi][ni][r] + bvs[ni]) * scz;
            int idx;
            if (mode == 0) {
              const int c = (mi2 * 2 + (dkl >> 5)) * 64 + ((dkl >> 3) & 3) * 16 + quad * 4 + r;
              idx = c * 8 + (dkl & 7);
            } else {
              const int c = (mi2 * 4 + (dkl >> 4)) * 64 + quad * 16 + (dkl & 15);
              idx = c * 4 + r;
            }
            pool[idx] = __float2bfloat16(v);
          }
        }
      }
#pragma unroll
      for (int t = 0; t < 4; ++t) {
        const short8 vv = *(const short8*)(pool + t * 512 + lane * 8);
        *(short8*)(outb + half2 * 2048 + t * 512 + lane * 8) = vv;
      }
    }
  }
}

// ---------------- V suffix sums ----------------
__global__ void suf_kernel(const bf16* __restrict__ vp, float* __restrict__ suf) {
  __shared__ float ts[32 * 64];
  const int bhid = blockIdx.x;
  const bf16* vb = vp + (size_t)bhid * HEADELEMS;
  const int tid = threadIdx.x;
  const int dk = tid & 63, g = tid >> 6;
  const int dkt = dk >> 4, lck = dk & 15;
  for (int T = g * 8; T < g * 8 + 8; ++T) {
    float sum = 0.f;
#pragma unroll
    for (int w = 0; w < 4; ++w)
#pragma unroll
      for (int qd = 0; qd < 4; ++qd) {
        const s4v x = *(const s4v*)(vb + (size_t)T * TILEELEMS
                                    + (size_t)(((w * 4 + dkt) * 64 + qd * 16 + lck)) * 4);
        sum += bs2f(x[0]) + bs2f(x[1]) + bs2f(x[2]) + bs2f(x[3]);
      }
    ts[T * 64 + dk] = sum;
  }
  __syncthreads();
  if (g == 0) {
    float run = 0.f;
    float* out = suf + (size_t)bhid * (33 * 64);
    out[32 * 64 + dk] = 0.f;
    for (int T = 31; T >= 0; --T) { run += ts[T * 64 + dk]; out[T * 64 + dk] = run; }
  }
}

// ---------------- fused attention ----------------
// 512 threads = 8 waves: wave (kw = w&3 key strip, qh = w>>2 q-half). Per wave:
// 2 qt, oacc[4][2] (32 regs) -> ~115 regs incl acc -> 16 waves/CU (4/SIMD).
// 1-key-tile steps, 4 LDS slots x 8192 elems (K [0,4096) | V [4096,8192)),
// depth-2 staging issued AFTER the step barrier (WAR-safe: writer of slot
// (T+2)&3 == (T-2)&3 only runs once ALL waves passed the step-T barrier, i.e.
// step T-1's readers of tile T-2 are done; step-T readers touch slots T&3 and
// (T-1)&3 only). One raw s_barrier + counted own-vmcnt per step.
template<bool DIAGP>
__device__ __forceinline__ void qk2(const short8 ak0, const short8 ak1,
                                    const short8 (&qf)[2][2],
                                    const unsigned int (&pmb)[4], const int T,
                                    short8 (&pB)[2], float (&lacc)[2], const int hlf,
                                    const int kw, const int qh,
                                    const int quad, const int lc, const bool diag) {
  const floatx4 z4 = {0.f, 0.f, 0.f, 0.f};
  const short ONE = (short)0x3F80;
#pragma unroll
  for (int qt = 0; qt < 2; ++qt) {
    const int qtg = qh * 2 + qt;
    if (DIAGP && diag && kw > qtg) {   // strictly-upper subtile: all masked -> p = 1
      s4v o1 = {ONE, ONE, ONE, ONE};
      ((s4v*)&pB[qt])[hlf] = o1;
      lacc[qt] += 4.f;
      continue;
    }
    floatx4 s = mfma16(ak0, qf[qt][0], z4);
    s = mfma16(ak1, qf[qt][1], s);
    float pv[4];
#pragma unroll
    for (int r = 0; r < 4; ++r) {
      bool m = ((pmb[r] >> T) & 1u) != 0u;
      if (DIAGP && diag && kw == qtg) m = m || (quad * 4 + r > lc);
      pv[r] = m ? 1.f : fast_exp2(s[r]);
      lacc[qt] += pv[r];
    }
    ((s4v*)&pB[qt])[hlf] = pack4(pv[0], pv[1], pv[2], pv[3]);
  }
}

__global__ __launch_bounds__(512, 4) void attn_kernel(
    const bf16* __restrict__ qp, const bf16* __restrict__ kp,
    const bf16* __restrict__ vp, const float* __restrict__ suf,
    const void* __restrict__ pad, const int* __restrict__ flag,
    bf16* __restrict__ oa)
{
  // 64KB: 4 staging slots x 8192 elems. Epilogue fbuf/obuf/lbuf alias slots 0-1.
  // Q staged pre-loop into slot3's K area (dead before step 1 restages slot 3).
  __shared__ __align__(16) bf16 lds[32768];

  const int lin = blockIdx.x;          // 512 blocks
  const int xcd = lin & 7;
  const int t = lin >> 3;              // 0..63
  const int grp = t >> 4;              // 0..3
  const int jq = t & 15;               // q-pair (31-jq, jq): tiles sum to 33 for all jq
  const int bh = xcd + 8 * grp;
  const int b = bh >> 4, h = bh & 15;

  const int tid = threadIdx.x;
  const int w = tid >> 6, lane = tid & 63, quad = lane >> 4, lc = lane & 15;
  const int kw = w & 3, qh = w >> 2;
  const int bytemode = *flag;

  const bf16* kb = kp + (size_t)bh * HEADELEMS;
  const bf16* vb = vp + (size_t)bh * HEADELEMS;
  const bf16* stgsrc = qh ? vb : kb;   // this wave stages K (qh=0) or V (qh=1) strip kw
  const int stgoff = kw * 1024;        // GLOBAL elem offset of strip kw within a tile
  const int stgdst = (qh ? 4096 : 0) + kw * 1024;   // LDS elem offset within slot

  // ---- pad mask bitmask: pmb[r] bit T = pad[b][T*64 + kw*16 + quad*4 + r] ----
  unsigned int pmb[4] = {0u, 0u, 0u, 0u};
  if (bytemode) {
    const unsigned char* pp = (const unsigned char*)pad + b * S_ + kw * 16 + quad * 4;
#pragma unroll
    for (int T = 0; T < 32; ++T) {
      const uchar4 u = *(const uchar4*)(pp + T * 64);
      pmb[0] |= (u.x ? 1u : 0u) << T;
      pmb[1] |= (u.y ? 1u : 0u) << T;
      pmb[2] |= (u.z ? 1u : 0u) << T;
      pmb[3] |= (u.w ? 1u : 0u) << T;
    }
  } else {
    const int* pp = (const int*)pad + b * S_ + kw * 16 + quad * 4;
#pragma unroll
    for (int T = 0; T < 32; ++T) {
      const int4 u = *(const int4*)(pp + (size_t)T * 64);
      pmb[0] |= (u.x ? 1u : 0u) << T;
      pmb[1] |= (u.y ? 1u : 0u) << T;
      pmb[2] |= (u.z ? 1u : 0u) << T;
      pmb[3] |= (u.w ? 1u : 0u) << T;
    }
  }

#pragma unroll 1
  for (int qsel = 0; qsel < 2; ++qsel) {
    const int myqt = qsel ? jq : 31 - jq;
    const int mynt = myqt + 1;           // key tiles (= steps)

    // ---- prologue: stage Q (slot3 K-area) + tiles 0,1 into slots 0,1 ----
    const bf16* qb = qp + (size_t)bh * HEADELEMS + (size_t)myqt * TILEELEMS;
    bf16* qarea = lds + 3 * 8192;
    gl_lds16(qb + w * 512 + lane * 8, qarea + w * 512);
    {
      const bf16* s0 = stgsrc + stgoff + lane * 8;                 // tile 0
      gl_lds16(s0, lds + stgdst);
      gl_lds16(s0 + 512, lds + stgdst + 512);
      if (mynt > 1) {
        const bf16* s1 = stgsrc + (size_t)TILEELEMS + stgoff + lane * 8;  // tile 1
        gl_lds16(s1, lds + 8192 + stgdst);
        gl_lds16(s1 + 512, lds + 8192 + stgdst + 512);
      }
    }
    if (mynt > 1) asm volatile("s_waitcnt vmcnt(4)" ::: "memory");  // Q landed
    else          asm volatile("s_waitcnt vmcnt(2)" ::: "memory");
    __builtin_amdgcn_s_barrier();        // everyone's Q slice in LDS
    __builtin_amdgcn_sched_barrier(0);

    short8 qf[2][2];
#pragma unroll
    for (int qt = 0; qt < 2; ++qt)
#pragma unroll
      for (int hh = 0; hh < 2; ++hh)
        qf[qt][hh] = *(const short8*)(qarea + (qh * 2 + qt) * 1024 + hh * 512 + lane * 8);
    asm volatile("s_waitcnt lgkmcnt(0)" ::: "memory");
    __builtin_amdgcn_sched_barrier(0);
    __builtin_amdgcn_s_barrier();        // all qf in regs before slot3 is restaged

    const floatx4 zero4 = {0.f, 0.f, 0.f, 0.f};
    floatx4 oacc[4][2];                  // [dkt][qt]
#pragma unroll
    for (int i = 0; i < 4; ++i)
#pragma unroll
      for (int jj = 0; jj < 2; ++jj) oacc[i][jj] = zero4;
    float lacc[2] = {0.f, 0.f};
    short8 pB[2];

#pragma unroll 1
    for (int T = 0; T < mynt; ++T) {
      // own tile-T loads landed; only tile T+1's 2 loads may remain in flight
      if (T + 1 < mynt) asm volatile("s_waitcnt vmcnt(2)" ::: "memory");
      else              asm volatile("s_waitcnt vmcnt(0)" ::: "memory");
      __builtin_amdgcn_s_barrier();      // all waves' tile-T data in LDS;
                                         // all step-(T-1) readers (tiles T-2,T-1) done
      __builtin_amdgcn_sched_barrier(0);

      if (T + 2 < mynt) {                // stage tile T+2 -> slot[(T+2)&3], POST-barrier
        bf16* sl = lds + (((T + 2) & 3) << 13) + stgdst;
        const bf16* src = stgsrc + (size_t)(T + 2) * TILEELEMS + stgoff + lane * 8;
        gl_lds16(src, sl);
        gl_lds16(src + 512, sl + 512);
      }

      const bf16* slot = lds + ((T & 3) << 13);
      const short8 ak0 = *(const short8*)(slot + kw * 1024 + lane * 8);
      const short8 ak1 = *(const short8*)(slot + kw * 1024 + 512 + lane * 8);

      const int hlf = T & 1;
      const bool diag = (T == mynt - 1);
      if (!diag) qk2<false>(ak0, ak1, qf, pmb, T, pB, lacc, hlf, kw, qh, quad, lc, false);
      else       qk2<true >(ak0, ak1, qf, pmb, T, pB, lacc, hlf, kw, qh, quad, lc, true);

      if (hlf == 1 || diag) {            // PV over the even/odd tile pair
        if (diag && hlf == 0) {          // phantom odd half: zero P, read VALID slot
          const s4v zz = {0, 0, 0, 0};
#pragma unroll
          for (int qt = 0; qt < 2; ++qt) ((s4v*)&pB[qt])[1] = zz;
        }
        const int Te = T & ~1;
        const bf16* se = lds + ((Te & 3) << 13);
        const bf16* so = (hlf == 1) ? slot : se;   // NaN-safe phantom source
        short8 av[4];
#pragma unroll
        for (int dkt = 0; dkt < 4; ++dkt) {
          ((s4v*)&av[dkt])[0] = *(const s4v*)(se + 4096 + kw * 1024 + dkt * 256 + lane * 4);
          ((s4v*)&av[dkt])[1] = *(const s4v*)(so + 4096 + kw * 1024 + dkt * 256 + lane * 4);
        }
#pragma unroll
        for (int dkt = 0; dkt < 4; ++dkt)
#pragma unroll
          for (int qt = 0; qt < 2; ++qt)
            oacc[dkt][qt] = mfma16(av[dkt], pB[qt], oacc[dkt][qt]);
      }
    }

    __syncthreads();   // all staging-slot reads done before epilogue aliases slots 0-1

    // ---- epilogue: cross-strip reduction -> LDS out-tile -> full-line stores ----
    // Alias slots 0-1: fbuf [0,17408)B, obuf [17408,26624)B, lbuf [26624,27648)B.
    float* fbuf = (float*)lds;
    bf16* obuf = lds + 8704;
    float* lbuf = (float*)(lds + 13312);

#pragma unroll
    for (int qt = 0; qt < 2; ++qt) {
      float v = lacc[qt];
      v += __shfl_xor(v, 16);
      v += __shfl_xor(v, 32);
      if (quad == 0) lbuf[(qh * 2 + qt) * 64 + kw * 16 + lc] = v;
    }
    __syncthreads();
    const int qtgR = w & 3;              // this wave reduces q-tile qtgR
    const int rh = w >> 2;               // dk-row half within each 16-row dkt block
    float ls = lbuf[qtgR * 64 + 0 * 16 + lc] + lbuf[qtgR * 64 + 1 * 16 + lc]
             + lbuf[qtgR * 64 + 2 * 16 + lc] + lbuf[qtgR * 64 + 3 * 16 + lc];
    ls += (float)(S_ - mynt * 64);       // keys past diagonal tile: weight 1 each
    const float linv = 1.f / ls;
    const float* sufp = suf + (size_t)bh * (33 * 64) + mynt * 64;

#pragma unroll
    for (int dktG = 0; dktG < 4; ++dktG) {
#pragma unroll
      for (int qt = 0; qt < 2; ++qt) {
        const floatx4 a = oacc[dktG][qt];
        float* dst = fbuf + (qh * 2 + qt) * 1088 + kw * 272 + lc;
#pragma unroll
        for (int r = 0; r < 4; ++r) dst[(quad * 4 + r) * 17] = a[r];   // stride 17: conflict-free
      }
      __syncthreads();
      const float2 sv = *(const float2*)(sufp + dktG * 16 + rh * 8 + quad * 2);
      float v0, v1;
      {
        const int e0 = qtgR * 1088 + (rh * 8 + quad * 2 + 0) * 17 + lc;
        const int e1 = qtgR * 1088 + (rh * 8 + quad * 2 + 1) * 17 + lc;
        v0 = fbuf[e0] + fbuf[e0 + 272] + fbuf[e0 + 544] + fbuf[e0 + 816];
        v1 = fbuf[e1] + fbuf[e1 + 272] + fbuf[e1 + 544] + fbuf[e1 + 816];
      }
      v0 = (v0 + sv.x) * linv;
      v1 = (v1 + sv.y) * linv;
      bf16x2 pk = { __float2bfloat16(v0), __float2bfloat16(v1) };
      *(bf16x2*)(obuf + (qtgR * 16 + lc) * 72 + dktG * 16 + rh * 8 + quad * 2) = pk;
      __syncthreads();
    }

    // store: 1 instruction per thread = 64 rows x 128B full lines
    const size_t obase = (size_t)(b * S_ + myqt * 64) * D_ + h * 64;
    {
      const int row = tid >> 3, c8 = (tid & 7) * 8;
      const short8 vv = *(const short8*)(obuf + row * 72 + c8);
      *(short8*)(oa + obase + (size_t)row * D_ + c8) = vv;
    }
    __syncthreads();   // epilogue LDS dead before next qsel's staging reuses it
  }
}

extern "C" void kernel_launch(void* const* d_in, const int* in_sizes, int n_in,
                              void* d_out, int out_size, void* d_ws, size_t ws_size,
                              hipStream_t stream) {
  (void)in_sizes; (void)n_in; (void)out_size; (void)ws_size;
  const float* q_in = (const float*)d_in[0];
  const float* k_in = (const float*)d_in[1];
  const float* v_in = (const float*)d_in[2];
  const void*  pmask = d_in[3];
  const float* Wq = (const float*)d_in[4];
  const float* bq = (const float*)d_in[5];
  const float* Wk = (const float*)d_in[6];
  const float* bk = (const float*)d_in[7];
  const float* Wv = (const float*)d_in[8];
  const float* bv = (const float*)d_in[9];
  const float* Wo = (const float*)d_in[10];
  const float* bo = (const float*)d_in[11];

  char* ws = (char*)d_ws;
  bf16* xq  = (bf16*)(ws + 0);
  bf16* xk  = (bf16*)(ws + 8388608);
  bf16* xv  = (bf16*)(ws + 16777216);
  bf16* wqt = (bf16*)(ws + 25165824);
  bf16* wkt = (bf16*)(ws + 27262976);
  bf16* wvt = (bf16*)(ws + 29360128);
  bf16* wot = (bf16*)(ws + 31457280);
  bf16* qpp = (bf16*)(ws + 33554432);
  bf16* kpp = (bf16*)(ws + 41943040);
  bf16* vpp = (bf16*)(ws + 50331648);
  float* suf = (float*)(ws + 25165824);   // overlays wqt (dead after projections)
  int*  flg = (int*)(ws + 58720256);
  bf16* oa  = xq;

  prep_kernel<<<13313, 256, 0, stream>>>(q_in, k_in, v_in, Wq, Wk, Wv, Wo,
                                         xq, xk, xv, wqt, wkt, wvt, wot,
                                         (const unsigned int*)pmask, flg);

  gemm_k<128><<<dim3(32, 8, 3), 256, 0, stream>>>(xq, xk, xv, wqt, wkt, wvt,
                                                  bq, bk, bv, qpp, kpp, vpp, 0, D_, QSCALE);
  suf_kernel<<<32, 256, 0, stream>>>(vpp, suf);

  attn_kernel<<<512, 512, 0, stream>>>(qpp, kpp, vpp, suf, pmask, flg, oa);

  gemm_k<128><<<dim3(32, 8, 1), 256, 0, stream>>>(oa, oa, oa, wot, wot, wot,
                                                  bo, bo, bo, d_out, d_out, d_out, 2, D_, 1.f);
}

// Round 7
// 214.535 us; speedup vs baseline: 1.3558x; 1.3558x over previous
//
#include <hip/hip_runtime.h>
#include <hip/hip_bf16.h>
#include <cstdint>
#include <cstddef>

typedef __hip_bfloat16 bf16;
typedef __attribute__((ext_vector_type(8))) short short8;   // 8 bf16 = 4 VGPRs
typedef __attribute__((ext_vector_type(4))) short s4v;      // 4 bf16 = 2 VGPRs
typedef __attribute__((ext_vector_type(4))) float floatx4;

#define B_ 2
#define S_ 2048
#define D_ 1024
#define H_ 16
#define DK_ 64
#define M_ 4096
#define HEADELEMS 131072   // S_*DK_ per (b,h)
#define TILEELEMS 4096     // 64*64 per 64-token tile
#define QSCALE 0.1803368801111204f   // 0.125 * log2(e), folded into Q projection

struct __align__(8) bf16x4 { bf16 x, y, z, w; };
struct __align__(4) bf16x2 { bf16 x, y; };

__device__ __forceinline__ floatx4 mfma16(short8 a, short8 b, floatx4 c) {
  return __builtin_amdgcn_mfma_f32_16x16x32_bf16(a, b, c, 0, 0, 0);
}
__device__ __forceinline__ void gl_lds16(const bf16* g, bf16* l) {
  __builtin_amdgcn_global_load_lds((const __attribute__((address_space(1))) void*)g,
                                   (__attribute__((address_space(3))) void*)l, 16, 0, 0);
}
__device__ __forceinline__ float bs2f(short s) {
  bf16 b = *reinterpret_cast<bf16*>(&s);
  return __bfloat162float(b);
}
__device__ __forceinline__ s4v pack4(float p0, float p1, float p2, float p3) {
  union { __hip_bfloat162 h; short2 s; } ua, ub;
  ua.h = __float22bfloat162_rn(make_float2(p0, p1));
  ub.h = __float22bfloat162_rn(make_float2(p2, p3));
  s4v r = {ua.s.x, ua.s.y, ub.s.x, ub.s.y};
  return r;
}
__device__ __forceinline__ float fast_exp2(float x) {
#if __has_builtin(__builtin_amdgcn_exp2f)
  return __builtin_amdgcn_exp2f(x);    // raw v_exp_f32 (no OCML range fixup)
#else
  float r; asm("v_exp_f32 %0, %1" : "=v"(r) : "v"(x)); return r;
#endif
}

// ---------------- fused prep: fp32->bf16 converts + weight transposes + mask detect ----------------
__global__ void prep_kernel(const float* __restrict__ q_in, const float* __restrict__ k_in,
                            const float* __restrict__ v_in,
                            const float* __restrict__ Wq, const float* __restrict__ Wk,
                            const float* __restrict__ Wv, const float* __restrict__ Wo,
                            bf16* __restrict__ xq, bf16* __restrict__ xk, bf16* __restrict__ xv,
                            bf16* __restrict__ wqt, bf16* __restrict__ wkt,
                            bf16* __restrict__ wvt, bf16* __restrict__ wot,
                            const unsigned int* __restrict__ pmask, int* __restrict__ flag) {
  __shared__ bf16 tile[64][66];
  __shared__ int sbyte;
  const int blk = blockIdx.x;
  const int tid = threadIdx.x;
  if (blk < 12288) {
    const int z = blk >> 12;
    const int i = ((blk & 4095) << 8) | tid;
    const float* src = (z == 0) ? q_in : (z == 1) ? k_in : v_in;
    bf16* dst = (z == 0) ? xq : (z == 1) ? xk : xv;
    float4 v = ((const float4*)src)[i];
    bf16x4 o = { __float2bfloat16(v.x), __float2bfloat16(v.y),
                 __float2bfloat16(v.z), __float2bfloat16(v.w) };
    ((bf16x4*)dst)[i] = o;
  } else if (blk < 13312) {
    const int t = blk - 12288;
    const int z = t >> 8;
    const int rc = t & 255;
    const int r0 = (rc >> 4) * 64, c0 = (rc & 15) * 64;
    const float* src = (z == 0) ? Wq : (z == 1) ? Wk : (z == 2) ? Wv : Wo;
    bf16* dst = (z == 0) ? wqt : (z == 1) ? wkt : (z == 2) ? wvt : wot;
    const int lr = tid >> 4;
    const int lc4 = (tid & 15) * 4;
#pragma unroll
    for (int i = 0; i < 4; ++i) {
      const int r = lr + i * 16;
      float4 v = *(const float4*)(src + (size_t)(r0 + r) * D_ + c0 + lc4);
      tile[r][lc4 + 0] = __float2bfloat16(v.x);
      tile[r][lc4 + 1] = __float2bfloat16(v.y);
      tile[r][lc4 + 2] = __float2bfloat16(v.z);
      tile[r][lc4 + 3] = __float2bfloat16(v.w);
    }
    __syncthreads();
    const int orr = tid & 63;
    const int oc0 = tid >> 6;
#pragma unroll
    for (int j = 0; j < 16; ++j) {
      const int oc = oc0 + j * 4;
      dst[(size_t)(c0 + oc) * D_ + r0 + orr] = tile[orr][oc];
    }
  } else {
    if (tid == 0) sbyte = 0;
    __syncthreads();
    for (int i = tid; i < (B_ * S_) / 4; i += 256) {
      const unsigned int v = pmask[i];
      if (((v & 0xFEFEFEFEu) == 0u) && ((v & 0xFFFFFF00u) != 0u)) sbyte = 1;
    }
    __syncthreads();
    if (tid == 0) *flag = sbyte;
  }
}

// ---------------- bf16 GEMM, C = A[M,K] * W[N,K]^T + bias ----------------
// BK=64 (128B LDS rows = bank cycle), XOR-swizzled staging (chunk ^= row&7) via
// pre-swizzled global_load_lds SOURCE addresses -> 2-way (free) ds_read_b128.
// Double-buffered 2-phase loop: stage(k+1) || ds_read+MFMA(k), one barrier/step.
// Grid (Mtiles, Ntiles, z): blockIdx.x = m-tile so the 8 blocks sharing an
// A-panel land on ONE XCD -> A-panel L2-local.
template<int MT>
__global__ __launch_bounds__(256, 2) void gemm_k(
    const bf16* __restrict__ A0, const bf16* __restrict__ A1, const bf16* __restrict__ A2,
    const bf16* __restrict__ W0, const bf16* __restrict__ W1, const bf16* __restrict__ W2,
    const float* __restrict__ b0, const float* __restrict__ b1, const float* __restrict__ b2,
    void* __restrict__ O0, void* __restrict__ O1, void* __restrict__ O2,
    const int mode01, const int Kd, const float sc)
{
  constexpr int ROWS = MT + 128;                    // A rows + B rows
  __shared__ __align__(16) bf16 sh[2 * ROWS * 64];  // two BK=64 buffers (64KB at MT=128)
  const int z = blockIdx.z;
  const bf16* A = (z == 0) ? A0 : (z == 1) ? A1 : A2;
  const bf16* W = (z == 0) ? W0 : (z == 1) ? W1 : W2;
  const float* bias = (z == 0) ? b0 : (z == 1) ? b1 : b2;
  void* Cout = (z == 0) ? O0 : (z == 1) ? O1 : O2;
  const int mode = (z == 2) ? 1 : mode01;
  const float scz = (z == 0) ? sc : 1.f;

  constexpr int MI = MT / 32;
  const int tid = threadIdx.x;
  const int wave = tid >> 6, lane = tid & 63;
  const int quad = lane >> 4, lc = lane & 15;
  const int wm = (wave >> 1) * (MT / 2), wn = (wave & 1) * 64;
  const int m0 = blockIdx.x * MT, n0 = blockIdx.y * 128;

  const floatx4 zero4 = {0.f, 0.f, 0.f, 0.f};
  floatx4 acc[MI][4];
#pragma unroll
  for (int mi = 0; mi < MI; ++mi)
#pragma unroll
    for (int ni = 0; ni < 4; ++ni) acc[mi][ni] = zero4;

  const int srow = lane >> 3;
  const int schunk = ((lane & 7) ^ srow) * 8;       // elems
  const bf16* Ag = A + (size_t)(m0 + wave * (MT / 4) + srow) * Kd + schunk;
  const bf16* Bg = W + (size_t)(n0 + wave * 32 + srow) * Kd + schunk;

  auto stage = [&](bf16* buf, int k0) {
    bf16* As0 = buf + wave * (MT / 4) * 64;
    bf16* Bs0 = buf + MT * 64 + wave * 32 * 64;
#pragma unroll
    for (int j = 0; j < MT / 32; ++j)
      gl_lds16(Ag + k0 + (size_t)(j * 8) * Kd, As0 + j * 512);
#pragma unroll
    for (int j = 0; j < 4; ++j)
      gl_lds16(Bg + k0 + (size_t)(j * 8) * Kd, Bs0 + j * 512);
  };

  stage(sh, 0);
  asm volatile("s_waitcnt vmcnt(0)" ::: "memory");
  __syncthreads();

  int cur = 0;
  for (int k0 = 0; k0 < Kd; k0 += 64) {
    bf16* cbuf = cur ? sh + ROWS * 64 : sh;
    bf16* nbuf = cur ? sh : sh + ROWS * 64;
    const bool more = (k0 + 64 < Kd);
    if (more) stage(nbuf, k0 + 64);                 // prefetch: hidden under reads+MFMA

    const bf16* Ar = cbuf;
    const bf16* Br = cbuf + MT * 64;
    short8 af[2][MI], bfr[2][4];
#pragma unroll
    for (int kk = 0; kk < 2; ++kk) {
#pragma unroll
      for (int i = 0; i < MI; ++i)
        af[kk][i] = *(const short8*)(Ar + (wm + i * 16 + lc) * 64
                                     + (((kk * 4 + quad) ^ (lc & 7)) * 8));
#pragma unroll
      for (int i = 0; i < 4; ++i)
        bfr[kk][i] = *(const short8*)(Br + (wn + i * 16 + lc) * 64
                                      + (((kk * 4 + quad) ^ (lc & 7)) * 8));
    }
#pragma unroll
    for (int kk = 0; kk < 2; ++kk)
#pragma unroll
      for (int mi = 0; mi < MI; ++mi)
#pragma unroll
        for (int ni = 0; ni < 4; ++ni)
          acc[mi][ni] = mfma16(af[kk][mi], bfr[kk][ni], acc[mi][ni]);

    __syncthreads();   // drains vmcnt(0): next buffer staged, this buffer free
    cur ^= 1;
  }

  if (mode == 2) {
    float* out = (float*)Cout;
#pragma unroll
    for (int mi = 0; mi < MI; ++mi)
#pragma unroll
      for (int ni = 0; ni < 4; ++ni) {
        const int col = n0 + wn + ni * 16 + lc;
        const float bv = bias[col];
        const int rbase = m0 + wm + mi * 16 + quad * 4;
#pragma unroll
        for (int r = 0; r < 4; ++r)
          out[(size_t)(rbase + r) * D_ + col] = acc[mi][ni][r] + bv;
      }
  } else {
    bf16* pool = sh + wave * 2048;
    float bvs[4];
#pragma unroll
    for (int ni = 0; ni < 4; ++ni) bvs[ni] = bias[n0 + wn + ni * 16 + lc];
    const int hcol = (n0 + wn) >> 6;
    const int mglob = m0 + wm;
    bf16* outb = (bf16*)Cout + (size_t)((mglob >> 11) * H_ + hcol) * HEADELEMS
               + (size_t)((mglob & (S_ - 1)) >> 6) * TILEELEMS;
#pragma unroll
    for (int half2 = 0; half2 < MI / 2; ++half2) {
#pragma unroll
      for (int mi2 = 0; mi2 < 2; ++mi2) {
        const int mi = half2 * 2 + mi2;
#pragma unroll
        for (int ni = 0; ni < 4; ++ni) {
          const int dkl = ni * 16 + lc;
#pragma unroll
          for (int r = 0; r < 4; ++r) {
            const float v = (acc[mi][ni][r] + bvs[ni]) * scz;
            int idx;
            if (mode == 0) {
              const int c = (mi2 * 2 + (dkl >> 5)) * 64 + ((dkl >> 3) & 3) * 16 + quad * 4 + r;
              idx = c * 8 + (dkl & 7);
            } else {
              const int c = (mi2 * 4 + (dkl >> 4)) * 64 + quad * 16 + (dkl & 15);
              idx = c * 4 + r;
            }
            pool[idx] = __float2bfloat16(v);
          }
        }
      }
#pragma unroll
      for (int t = 0; t < 4; ++t) {
        const short8 vv = *(const short8*)(pool + t * 512 + lane * 8);
        *(short8*)(outb + half2 * 2048 + t * 512 + lane * 8) = vv;
      }
    }
  }
}

// ---------------- V suffix sums ----------------
__global__ void suf_kernel(const bf16* __restrict__ vp, float* __restrict__ suf) {
  __shared__ float ts[32 * 64];
  const int bhid = blockIdx.x;
  const bf16* vb = vp + (size_t)bhid * HEADELEMS;
  const int tid = threadIdx.x;
  const int dk = tid & 63, g = tid >> 6;
  const int dkt = dk >> 4, lck = dk & 15;
  for (int T = g * 8; T < g * 8 + 8; ++T) {
    float sum = 0.f;
#pragma unroll
    for (int w = 0; w < 4; ++w)
#pragma unroll
      for (int qd = 0; qd < 4; ++qd) {
        const s4v x = *(const s4v*)(vb + (size_t)T * TILEELEMS
                                    + (size_t)(((w * 4 + dkt) * 64 + qd * 16 + lck)) * 4);
        sum += bs2f(x[0]) + bs2f(x[1]) + bs2f(x[2]) + bs2f(x[3]);
      }
    ts[T * 64 + dk] = sum;
  }
  __syncthreads();
  if (g == 0) {
    float run = 0.f;
    float* out = suf + (size_t)bhid * (33 * 64);
    out[32 * 64 + dk] = 0.f;
    for (int T = 31; T >= 0; --T) { run += ts[T * 64 + dk]; out[T * 64 + dk] = run; }
  }
}

// ---------------- fused attention ----------------
// 512 threads = 8 waves: wave (kw = w&3 key strip, qh = w>>2 q-half). Per wave:
// 2 qt, oacc[4][2] -> ~90-120 regs, no spill (ALL vector indices compile-time;
// R6's runtime-hlf indexing spilled pB to scratch: VGPR 64 + 6MB scratch traffic).
// PAIR steps (2 key tiles, R4 structure): two 32KB slots [K0|K1|V0|V1], 17 steps,
// one vmcnt(0)+s_barrier per step, staging issued POST-barrier (WAR-safe), split
// across waves: qh=0 stages K strips, qh=1 stages V strips (4 loads/wave/step).
// 2 blocks/CU x 8 waves = 16 waves/CU = 4 waves/SIMD (vs R4's 2): 2x latency hiding.
template<bool DIAGP>
__device__ __forceinline__ void qk2(const short8 ak0, const short8 ak1,
                                    const short8 (&qf)[2][2],
                                    const unsigned int (&pmb)[4], const int T,
                                    s4v (&pf)[2], float (&lacc)[2],
                                    const int kw, const int qh,
                                    const int quad, const int lc, const bool diag) {
  const floatx4 z4 = {0.f, 0.f, 0.f, 0.f};
  const short ONE = (short)0x3F80;
#pragma unroll
  for (int qt = 0; qt < 2; ++qt) {
    const int qtg = qh * 2 + qt;
    if (DIAGP && diag && kw > qtg) {   // strictly-upper subtile: all masked -> p = 1
      s4v o1 = {ONE, ONE, ONE, ONE};
      pf[qt] = o1;
      lacc[qt] += 4.f;
      continue;
    }
    floatx4 s = mfma16(ak0, qf[qt][0], z4);
    s = mfma16(ak1, qf[qt][1], s);
    float pv[4];
#pragma unroll
    for (int r = 0; r < 4; ++r) {
      bool m = ((pmb[r] >> T) & 1u) != 0u;
      if (DIAGP && diag && kw == qtg) m = m || (quad * 4 + r > lc);
      pv[r] = m ? 1.f : fast_exp2(s[r]);
      lacc[qt] += pv[r];
    }
    pf[qt] = pack4(pv[0], pv[1], pv[2], pv[3]);
  }
}

__global__ __launch_bounds__(512, 4) void attn_kernel(
    const bf16* __restrict__ qp, const bf16* __restrict__ kp,
    const bf16* __restrict__ vp, const float* __restrict__ suf,
    const void* __restrict__ pad, const int* __restrict__ flag,
    bf16* __restrict__ oa)
{
  // 64KB: two 32KB pair slots. Epilogue fbuf/obuf/lbuf alias slot 0.
  // Q staged pre-loop into slot1's K0 area (dead before step 0 restages slot 1).
  __shared__ __align__(16) bf16 lds[32768];

  const int lin = blockIdx.x;          // 512 blocks
  const int xcd = lin & 7;
  const int t = lin >> 3;              // 0..63
  const int grp = t >> 4;              // 0..3
  const int jq = t & 15;               // q-pair (31-jq, jq): pair-steps sum to 17
  const int bh = xcd + 8 * grp;
  const int b = bh >> 4, h = bh & 15;

  const int tid = threadIdx.x;
  const int w = tid >> 6, lane = tid & 63, quad = lane >> 4, lc = lane & 15;
  const int kw = w & 3, qh = w >> 2;
  const int bytemode = *flag;

  const bf16* kb = kp + (size_t)bh * HEADELEMS;
  const bf16* vb = vp + (size_t)bh * HEADELEMS;
  const bf16* stgsrc = qh ? vb : kb;   // qh=0 waves stage K strips, qh=1 stage V strips
  const int stgbase = qh ? 8192 : 0;   // LDS elem offset of the K/V region in a slot

  // ---- pad mask bitmask: pmb[r] bit T = pad[b][T*64 + kw*16 + quad*4 + r] ----
  unsigned int pmb[4] = {0u, 0u, 0u, 0u};
  if (bytemode) {
    const unsigned char* pp = (const unsigned char*)pad + b * S_ + kw * 16 + quad * 4;
#pragma unroll
    for (int T = 0; T < 32; ++T) {
      const uchar4 u = *(const uchar4*)(pp + T * 64);
      pmb[0] |= (u.x ? 1u : 0u) << T;
      pmb[1] |= (u.y ? 1u : 0u) << T;
      pmb[2] |= (u.z ? 1u : 0u) << T;
      pmb[3] |= (u.w ? 1u : 0u) << T;
    }
  } else {
    const int* pp = (const int*)pad + b * S_ + kw * 16 + quad * 4;
#pragma unroll
    for (int T = 0; T < 32; ++T) {
      const int4 u = *(const int4*)(pp + (size_t)T * 64);
      pmb[0] |= (u.x ? 1u : 0u) << T;
      pmb[1] |= (u.y ? 1u : 0u) << T;
      pmb[2] |= (u.z ? 1u : 0u) << T;
      pmb[3] |= (u.w ? 1u : 0u) << T;
    }
  }

#pragma unroll 1
  for (int qsel = 0; qsel < 2; ++qsel) {
    const int myqt = qsel ? jq : 31 - jq;
    const int mynt = myqt + 1;           // key tiles
    const int np = (mynt + 1) >> 1;      // pair steps

    // ---- prologue: stage Q (slot1 K0 area, 8 waves x 1 load) + pair 0 into slot 0 ----
    const bf16* qb = qp + (size_t)bh * HEADELEMS + (size_t)myqt * TILEELEMS;
    bf16* qarea = lds + 16384;
    gl_lds16(qb + w * 512 + lane * 8, qarea + w * 512);
    {
      const bf16* s0 = stgsrc + kw * 1024 + lane * 8;                  // tile 0
      bf16* d0 = lds + stgbase + kw * 1024;
      gl_lds16(s0, d0);
      gl_lds16(s0 + 512, d0 + 512);
      const bf16* s1 = stgsrc + TILEELEMS + kw * 1024 + lane * 8;      // tile 1 (always valid)
      gl_lds16(s1, d0 + 4096);
      gl_lds16(s1 + 512, d0 + 4096 + 512);
    }
    asm volatile("s_waitcnt vmcnt(4)" ::: "memory");   // Q (oldest) landed
    __builtin_amdgcn_s_barrier();        // everyone's Q slice in LDS
    __builtin_amdgcn_sched_barrier(0);

    short8 qf[2][2];
#pragma unroll
    for (int qt = 0; qt < 2; ++qt)
#pragma unroll
      for (int hh = 0; hh < 2; ++hh)
        qf[qt][hh] = *(const short8*)(qarea + (qh * 2 + qt) * 1024 + hh * 512 + lane * 8);
    asm volatile("s_waitcnt lgkmcnt(0)" ::: "memory");
    __builtin_amdgcn_sched_barrier(0);
    __builtin_amdgcn_s_barrier();        // all qf in regs before slot1 is restaged

    const floatx4 zero4 = {0.f, 0.f, 0.f, 0.f};
    floatx4 oacc[4][2];                  // [dkt][qt]
#pragma unroll
    for (int i = 0; i < 4; ++i)
#pragma unroll
      for (int jj = 0; jj < 2; ++jj) oacc[i][jj] = zero4;
    float lacc[2] = {0.f, 0.f};

#pragma unroll 1
    for (int p = 0; p < np; ++p) {
      asm volatile("s_waitcnt vmcnt(0)" ::: "memory");  // own pair-p loads landed
      __builtin_amdgcn_s_barrier();      // all waves' pair-p data in LDS;
                                         // all step-(p-1) compute done everywhere
      __builtin_amdgcn_sched_barrier(0);

      if (p + 1 < np) {                  // stage pair p+1 -> slot[(p+1)&1], POST-barrier
        bf16* sl = lds + (((p + 1) & 1) << 14) + stgbase + kw * 1024;
        const bf16* src = stgsrc + (size_t)(2 * p + 2) * TILEELEMS + kw * 1024 + lane * 8;
        gl_lds16(src, sl);
        gl_lds16(src + 512, sl + 512);
        const bf16* src2 = src + TILEELEMS;
        gl_lds16(src2, sl + 4096);
        gl_lds16(src2 + 512, sl + 4096 + 512);
      }

      const bf16* slot = lds + ((p & 1) << 14);
      const bf16* kstrip = slot + kw * 1024;
      const short8 ak00 = *(const short8*)(kstrip + lane * 8);
      const short8 ak01 = *(const short8*)(kstrip + 512 + lane * 8);
      const short8 ak10 = *(const short8*)(kstrip + 4096 + lane * 8);
      const short8 ak11 = *(const short8*)(kstrip + 4096 + 512 + lane * 8);

      const int T0 = 2 * p, T1 = 2 * p + 1;
      s4v pf0[2], pf1[2];
      if (p + 1 < np) {
        qk2<false>(ak00, ak01, qf, pmb, T0, pf0, lacc, kw, qh, quad, lc, false);
        qk2<false>(ak10, ak11, qf, pmb, T1, pf1, lacc, kw, qh, quad, lc, false);
      } else {  // tail pair: contains the diagonal tile (phantom T1 when mynt odd)
        qk2<true>(ak00, ak01, qf, pmb, T0, pf0, lacc, kw, qh, quad, lc, T0 == mynt - 1);
        if (T1 < mynt) {
          qk2<true>(ak10, ak11, qf, pmb, T1, pf1, lacc, kw, qh, quad, lc, true);
        } else {
          const s4v zz = {0, 0, 0, 0};
          pf1[0] = zz; pf1[1] = zz;      // phantom: suffix sums cover
        }
      }
      short8 pB[2];                      // STATIC half indices only (no spill)
      ((s4v*)&pB[0])[0] = pf0[0]; ((s4v*)&pB[0])[1] = pf1[0];
      ((s4v*)&pB[1])[0] = pf0[1]; ((s4v*)&pB[1])[1] = pf1[1];

      const bf16* vstrip = slot + 8192 + kw * 1024;
      short8 av[4];
#pragma unroll
      for (int dkt = 0; dkt < 4; ++dkt) {
        ((s4v*)&av[dkt])[0] = *(const s4v*)(vstrip + dkt * 256 + lane * 4);
        ((s4v*)&av[dkt])[1] = *(const s4v*)(vstrip + 4096 + dkt * 256 + lane * 4);
      }
#pragma unroll
      for (int dkt = 0; dkt < 4; ++dkt)
#pragma unroll
        for (int qt = 0; qt < 2; ++qt)
          oacc[dkt][qt] = mfma16(av[dkt], pB[qt], oacc[dkt][qt]);
    }

    __syncthreads();   // all staging-slot reads done before epilogue aliases slot 0

    // ---- epilogue: cross-strip reduction -> LDS out-tile -> full-line stores ----
    // Alias slot 0: fbuf [0,17408)B, obuf [17408,26624)B, lbuf [26624,27648)B.
    float* fbuf = (float*)lds;
    bf16* obuf = lds + 8704;
    float* lbuf = (float*)(lds + 13312);

#pragma unroll
    for (int qt = 0; qt < 2; ++qt) {
      float v = lacc[qt];
      v += __shfl_xor(v, 16);
      v += __shfl_xor(v, 32);
      if (quad == 0) lbuf[(qh * 2 + qt) * 64 + kw * 16 + lc] = v;
    }
    __syncthreads();
    const int qtgR = w & 3;              // this wave reduces q-tile qtgR
    const int rh = w >> 2;               // dk-row half within each 16-row dkt block
    float ls = lbuf[qtgR * 64 + 0 * 16 + lc] + lbuf[qtgR * 64 + 1 * 16 + lc]
             + lbuf[qtgR * 64 + 2 * 16 + lc] + lbuf[qtgR * 64 + 3 * 16 + lc];
    ls += (float)(S_ - mynt * 64);       // keys past diagonal tile: weight 1 each
    const float linv = 1.f / ls;
    const float* sufp = suf + (size_t)bh * (33 * 64) + mynt * 64;

#pragma unroll
    for (int dktG = 0; dktG < 4; ++dktG) {
#pragma unroll
      for (int qt = 0; qt < 2; ++qt) {
        const floatx4 a = oacc[dktG][qt];
        float* dst = fbuf + (qh * 2 + qt) * 1088 + kw * 272 + lc;
#pragma unroll
        for (int r = 0; r < 4; ++r) dst[(quad * 4 + r) * 17] = a[r];   // stride 17: conflict-free
      }
      __syncthreads();
      const float2 sv = *(const float2*)(sufp + dktG * 16 + rh * 8 + quad * 2);
      float v0, v1;
      {
        const int e0 = qtgR * 1088 + (rh * 8 + quad * 2 + 0) * 17 + lc;
        const int e1 = qtgR * 1088 + (rh * 8 + quad * 2 + 1) * 17 + lc;
        v0 = fbuf[e0] + fbuf[e0 + 272] + fbuf[e0 + 544] + fbuf[e0 + 816];
        v1 = fbuf[e1] + fbuf[e1 + 272] + fbuf[e1 + 544] + fbuf[e1 + 816];
      }
      v0 = (v0 + sv.x) * linv;
      v1 = (v1 + sv.y) * linv;
      bf16x2 pk = { __float2bfloat16(v0), __float2bfloat16(v1) };
      *(bf16x2*)(obuf + (qtgR * 16 + lc) * 72 + dktG * 16 + rh * 8 + quad * 2) = pk;
      __syncthreads();
    }

    // store: 1 instruction per thread = 64 rows x 128B full lines
    const size_t obase = (size_t)(b * S_ + myqt * 64) * D_ + h * 64;
    {
      const int row = tid >> 3, c8 = (tid & 7) * 8;
      const short8 vv = *(const short8*)(obuf + row * 72 + c8);
      *(short8*)(oa + obase + (size_t)row * D_ + c8) = vv;
    }
    __syncthreads();   // epilogue LDS dead before next qsel's staging reuses it
  }
}

extern "C" void kernel_launch(void* const* d_in, const int* in_sizes, int n_in,
                              void* d_out, int out_size, void* d_ws, size_t ws_size,
                              hipStream_t stream) {
  (void)in_sizes; (void)n_in; (void)out_size; (void)ws_size;
  const float* q_in = (const float*)d_in[0];
  const float* k_in = (const float*)d_in[1];
  const float* v_in = (const float*)d_in[2];
  const void*  pmask = d_in[3];
  const float* Wq = (const float*)d_in[4];
  const float* bq = (const float*)d_in[5];
  const float* Wk = (const float*)d_in[6];
  const float* bk = (const float*)d_in[7];
  const float* Wv = (const float*)d_in[8];
  const float* bv = (const float*)d_in[9];
  const float* Wo = (const float*)d_in[10];
  const float* bo = (const float*)d_in[11];

  char* ws = (char*)d_ws;
  bf16* xq  = (bf16*)(ws + 0);
  bf16* xk  = (bf16*)(ws + 8388608);
  bf16* xv  = (bf16*)(ws + 16777216);
  bf16* wqt = (bf16*)(ws + 25165824);
  bf16* wkt = (bf16*)(ws + 27262976);
  bf16* wvt = (bf16*)(ws + 29360128);
  bf16* wot = (bf16*)(ws + 31457280);
  bf16* qpp = (bf16*)(ws + 33554432);
  bf16* kpp = (bf16*)(ws + 41943040);
  bf16* vpp = (bf16*)(ws + 50331648);
  float* suf = (float*)(ws + 25165824);   // overlays wqt (dead after projections)
  int*  flg = (int*)(ws + 58720256);
  bf16* oa  = xq;

  prep_kernel<<<13313, 256, 0, stream>>>(q_in, k_in, v_in, Wq, Wk, Wv, Wo,
                                         xq, xk, xv, wqt, wkt, wvt, wot,
                                         (const unsigned int*)pmask, flg);

  gemm_k<128><<<dim3(32, 8, 3), 256, 0, stream>>>(xq, xk, xv, wqt, wkt, wvt,
                                                  bq, bk, bv, qpp, kpp, vpp, 0, D_, QSCALE);
  suf_kernel<<<32, 256, 0, stream>>>(vpp, suf);

  attn_kernel<<<512, 512, 0, stream>>>(qpp, kpp, vpp, suf, pmask, flg, oa);

  gemm_k<128><<<dim3(32, 8, 1), 256, 0, stream>>>(oa, oa, oa, wot, wot, wot,
                                                  bo, bo, bo, d_out, d_out, d_out, 2, D_, 1.f);
}